// Round 9
// baseline (602.147 us; speedup 1.0000x reference)
//
#include <hip/hip_runtime.h>
#include <stdint.h>

#define BATCH 4096
#define DIM   1024
#define PPREV 8
#define CAPW  64    // per-wave candidate capacity

// popcount of mask over lanes strictly below the current lane
__device__ __forceinline__ int lt_count(unsigned long long m) {
    return __builtin_amdgcn_mbcnt_hi((unsigned)(m >> 32),
           __builtin_amdgcn_mbcnt_lo((unsigned)m, 0));
}
__device__ __forceinline__ bool kp_gt(int ak, int ap, int bk, int bp) {
    return (ak > bk) || (ak == bk && ap > bp);
}

// ============================================================================
// Block-cooperative top-10 by |value|, exact jax.lax.top_k tie-break (lowest
// flat index wins among ties). 256 threads/row; thread owns j = tid*4+t.
// Key = |f32 bits| (int compare == magnitude compare);
// payload = ((1023-j)<<1)|sign -> (key,pay) lex-desc == (value desc, idx asc).
// Fast path: 2 barriers (compact+count | rank+winners).
// ============================================================================
template<bool SEEDED>
__device__ __forceinline__ void select10_blk(
    const float cz[4], int tid, int lane, int wid,
    int2 (*s_cand)[CAPW], int2* s_win, int* s_cnt, int2* s_red, int* s_bnd,
    int& tbits, int wi[10], float wv[10])
{
    int k[4], pay[4];
    #pragma unroll
    for (int t = 0; t < 4; ++t) {
        int bb = __float_as_int(cz[t]);
        k[t]   = bb & 0x7fffffff;
        pay[t] = ((1023 - (tid * 4 + t)) << 1) | (int)((unsigned)bb >> 31);
    }

    if (!SEEDED) {
        // valid lower bound for the 10th-largest: per wave, the 10th-largest
        // of its 64 per-lane maxima (10 distinct elements >= it); block bound
        // = max over waves (the achieving wave provides the 10 witnesses).
        int lm = max(max(k[0], k[1]), max(k[2], k[3]));
        #pragma unroll
        for (int k2 = 2; k2 <= 64; k2 <<= 1) {
            #pragma unroll
            for (int j = k2 >> 1; j > 0; j >>= 1) {
                int p = __shfl_xor(lm, j);
                bool keep_max = (((lane & k2) == 0) == ((lane & j) == 0));
                if ((p > lm) == keep_max) lm = p;
            }
        }
        int wb = __builtin_amdgcn_readlane(lm, 9);
        if (lane == 0) s_bnd[wid] = wb;
        __syncthreads();
        tbits = max(max(s_bnd[0], s_bnd[1]), max(s_bnd[2], s_bnd[3]));
    }

    int tb = tbits;
    int c0, c1, c2, c3, total; bool bad;
    #pragma unroll 1
    for (;;) {
        unsigned long long b0 = __ballot(k[0] >= tb);
        unsigned long long b1 = __ballot(k[1] >= tb);
        unsigned long long b2 = __ballot(k[2] >= tb);
        unsigned long long b3 = __ballot(k[3] >= tb);
        // fused compact into this wave's region (clamped; clamp only fires
        // when wcnt > CAPW which forces the fallback path anyway)
        int pos = lt_count(b0);
        if (k[0] >= tb && pos < CAPW) s_cand[wid][pos] = make_int2(k[0], pay[0]);
        int base = __popcll(b0);
        pos = base + lt_count(b1);
        if (k[1] >= tb && pos < CAPW) s_cand[wid][pos] = make_int2(k[1], pay[1]);
        base += __popcll(b1);
        pos = base + lt_count(b2);
        if (k[2] >= tb && pos < CAPW) s_cand[wid][pos] = make_int2(k[2], pay[2]);
        base += __popcll(b2);
        pos = base + lt_count(b3);
        if (k[3] >= tb && pos < CAPW) s_cand[wid][pos] = make_int2(k[3], pay[3]);
        base += __popcll(b3);
        if (lane == 0) s_cnt[wid] = base;
        __syncthreads();                               // barrier 1
        c0 = s_cnt[0]; c1 = s_cnt[1]; c2 = s_cnt[2]; c3 = s_cnt[3];
        total = c0 + c1 + c2 + c3;
        bad = (c0 > CAPW) || (c1 > CAPW) || (c2 > CAPW) || (c3 > CAPW);
        if (total >= 10 || tb == 0) break;
        tb = (tb > 0x00800000) ? (tb - 0x00800000) : 0;   // halve threshold
        __syncthreads();   // protect s_cand/s_cnt rewrite from stragglers
    }

    if (!bad) {
        // exact rank by broadcast LDS reads (candidates all distinct via pay)
        if (tid < total) {
            int w, e;
            if      (tid < c0)           { w = 0; e = tid; }
            else if (tid < c0 + c1)      { w = 1; e = tid - c0; }
            else if (tid < c0 + c1 + c2) { w = 2; e = tid - c0 - c1; }
            else                         { w = 3; e = tid - c0 - c1 - c2; }
            int2 mine = s_cand[w][e];
            int cns[4] = {c0, c1, c2, c3};
            int rank = 0;
            #pragma unroll
            for (int w2 = 0; w2 < 4; ++w2) {
                const int cn = cns[w2];
                const int2* reg = s_cand[w2];
                int e2 = 0;
                #pragma unroll 1
                for (; e2 + 4 <= cn; e2 += 4) {
                    int2 q0 = reg[e2], q1 = reg[e2+1], q2 = reg[e2+2], q3 = reg[e2+3];
                    rank += kp_gt(q0.x, q0.y, mine.x, mine.y) ? 1 : 0;
                    rank += kp_gt(q1.x, q1.y, mine.x, mine.y) ? 1 : 0;
                    rank += kp_gt(q2.x, q2.y, mine.x, mine.y) ? 1 : 0;
                    rank += kp_gt(q3.x, q3.y, mine.x, mine.y) ? 1 : 0;
                }
                #pragma unroll 1
                for (; e2 < cn; ++e2) {
                    int2 q = reg[e2];
                    rank += kp_gt(q.x, q.y, mine.x, mine.y) ? 1 : 0;
                }
            }
            if (rank < 10) s_win[rank] = mine;   // strict order -> unique ranks
        }
        __syncthreads();                               // barrier 2
    } else {
        // rare fallback: 10 rounds of exact block argmax
        #pragma unroll 1
        for (int r = 0; r < 10; ++r) {
            int bk = k[0], bp = pay[0];
            #pragma unroll
            for (int t = 1; t < 4; ++t)
                if (kp_gt(k[t], pay[t], bk, bp)) { bk = k[t]; bp = pay[t]; }
            #pragma unroll
            for (int m = 1; m < 64; m <<= 1) {
                int ok = __shfl_xor(bk, m), op = __shfl_xor(bp, m);
                if (kp_gt(ok, op, bk, bp)) { bk = ok; bp = op; }
            }
            if (lane == 0) s_red[wid] = make_int2(bk, bp);
            __syncthreads();
            if (tid == 0) {
                int2 best = s_red[0];
                #pragma unroll
                for (int w2 = 1; w2 < 4; ++w2) {
                    int2 cc = s_red[w2];
                    if (kp_gt(cc.x, cc.y, best.x, best.y)) best = cc;
                }
                s_win[r] = best;
            }
            __syncthreads();
            int2 wr = s_win[r];
            #pragma unroll
            for (int t = 0; t < 4; ++t)
                if (k[t] == wr.x && pay[t] == wr.y) k[t] = -1;   // pay unique
        }
    }

    #pragma unroll
    for (int r = 0; r < 10; ++r) {
        int2 wr = s_win[r];
        wi[r] = 1023 - (wr.y >> 1);
        wv[r] = __int_as_float(wr.x | ((wr.y & 1) << 31));
    }
    tbits = __float_as_int(wv[9]) & 0x7fffffff;
}

// c = b + sum_k wv[k] * S[wi[k], :]  (S numerically symmetric -> row access;
// wi block-uniform -> scalar base addressing; coalesced float4 per thread)
__device__ __forceinline__ void gather_block(const float bz[4], float cz[4],
                                             const float* __restrict__ S,
                                             const int wi[10], const float wv[10], int tid)
{
    #pragma unroll
    for (int t = 0; t < 4; ++t) cz[t] = bz[t];
    #pragma unroll
    for (int kk = 0; kk < 10; ++kk) {
        int row = __builtin_amdgcn_readfirstlane(wi[kk]);
        const float wvs = wv[kk];
        float4 v = *(const float4*)(S + (size_t)row * DIM + tid * 4);
        cz[0] += wvs * v.x;
        cz[1] += wvs * v.y;
        cz[2] += wvs * v.z;
        cz[3] += wvs * v.w;
    }
}

// ============================================================================
// Warm-up: z=thr(b); c=b+z@S^T; z=thr(c) -> sparse (idx,val). 1 block/row.
// ============================================================================
__global__ __launch_bounds__(256)
void warmup_rows(const float* __restrict__ b, const float* __restrict__ S,
                 int* __restrict__ sidx, float* __restrict__ sval)
{
    __shared__ int2 s_cand[4][CAPW];
    __shared__ int2 s_win[10];
    __shared__ int2 s_red[4];
    __shared__ int  s_cnt[4];
    __shared__ int  s_bnd[4];
    const int tid = threadIdx.x, lane = tid & 63, wid = tid >> 6;
    const int r = blockIdx.x;
    float4 bv = *(const float4*)(b + (size_t)r * DIM + tid * 4);
    float bz[4] = {bv.x, bv.y, bv.z, bv.w};
    int wi[10]; float wv[10]; int tbits = 0;
    select10_blk<false>(bz, tid, lane, wid, s_cand, s_win, s_cnt, s_red, s_bnd, tbits, wi, wv);
    float cz[4];
    gather_block(bz, cz, S, wi, wv, tid);
    select10_blk<true>(cz, tid, lane, wid, s_cand, s_win, s_cnt, s_red, s_bnd, tbits, wi, wv);
    if (tid < 10) {
        int2 wr = s_win[tid];
        sidx[r * 10 + tid] = 1023 - (wr.y >> 1);
        sval[r * 10 + tid] = __int_as_float(wr.x | ((wr.y & 1) << 31));
    }
}

// ============================================================================
// Main loop: z=thr(c1); 9 x { c=b+z@S^T; z=thr(c) } with exact fixed-point
// early exit (block-uniform). Writes dense z + sparse. 1 block/row.
// ============================================================================
__global__ __launch_bounds__(256)
void loop_rows(const float* __restrict__ c1, const float* __restrict__ b,
               const float* __restrict__ S, float* __restrict__ zout,
               int* __restrict__ sidx, float* __restrict__ sval)
{
    __shared__ int2 s_cand[4][CAPW];
    __shared__ int2 s_win[10];
    __shared__ int2 s_red[4];
    __shared__ int  s_cnt[4];
    __shared__ int  s_bnd[4];
    const int tid = threadIdx.x, lane = tid & 63, wid = tid >> 6;
    const int r = blockIdx.x;
    float4 bv = *(const float4*)(b  + (size_t)r * DIM + tid * 4);
    float4 cv = *(const float4*)(c1 + (size_t)r * DIM + tid * 4);
    float bz[4] = {bv.x, bv.y, bv.z, bv.w};
    float cz[4] = {cv.x, cv.y, cv.z, cv.w};
    int wi[10]; float wv[10]; int tbits = 0;
    select10_blk<false>(cz, tid, lane, wid, s_cand, s_win, s_cnt, s_red, s_bnd, tbits, wi, wv);
    int pwi[10], pwb[10];
    #pragma unroll 1
    for (int it = 0; it < 9; ++it) {
        #pragma unroll
        for (int kk = 0; kk < 10; ++kk) { pwi[kk] = wi[kk]; pwb[kk] = __float_as_int(wv[kk]); }
        gather_block(bz, cz, S, wi, wv, tid);
        select10_blk<true>(cz, tid, lane, wid, s_cand, s_win, s_cnt, s_red, s_bnd, tbits, wi, wv);
        bool same = true;
        #pragma unroll
        for (int kk = 0; kk < 10; ++kk)
            same = same && (wi[kk] == pwi[kk]) && (__float_as_int(wv[kk]) == pwb[kk]);
        if (same) break;   // exact fixed point: remaining iterations identical
    }
    float e[4];
    #pragma unroll
    for (int t = 0; t < 4; ++t) {
        const int j = tid * 4 + t;
        float v = 0.0f;
        #pragma unroll
        for (int kk = 0; kk < 10; ++kk) v = (wi[kk] == j) ? wv[kk] : v;
        e[t] = v;
    }
    float4 o; o.x = e[0]; o.y = e[1]; o.z = e[2]; o.w = e[3];
    *(float4*)(zout + (size_t)r * DIM + tid * 4) = o;
    if (tid < 10) {
        int2 wr = s_win[tid];
        sidx[r * 10 + tid] = 1023 - (wr.y >> 1);
        sval[r * 10 + tid] = __int_as_float(wr.x | ((wr.y & 1) << 31));
    }
}

// ============================================================================
// GEMM: C[m,n] = (sum_k A[m,k]*B[n,k]) [/L] [+ add[m,n]]  (C = A @ B^T)
// 128x64 tile, BK=16, 256 threads (4 waves), 8x4 per thread.
// Wave = 8x8 lane grid over a 64x32 quadrant; BOTH LDS operand reads are
// 8-address multicast, and columns are stored at cmap(m)=m+(m>>5)*4 so the
// 8 addresses hit 8 DISTINCT bank groups (32/32 banks, zero read conflicts).
// Double-buffered, ONE barrier per K-tile, register prefetch.
// Grid 512 = 2 blocks/CU = 8 waves/CU = 2 waves/SIMD.
// ============================================================================
template<bool DIV_L, bool HAS_ADD>
__global__ __launch_bounds__(256)
void gemm_cf(const float* __restrict__ A, const float* __restrict__ B,
             const float* __restrict__ addM, float* __restrict__ C,
             const float* __restrict__ Lptr, int M, int N, int K)
{
    __shared__ __align__(16) float As[2][16][140];   // 128 cols, cmap<=139
    __shared__ __align__(16) float Bs[2][16][68];    // 64 cols,  cmap<=67
    const int tid  = threadIdx.x;                    // 0..255
    const int lane = tid & 63, w = tid >> 6;
    const int wy = lane >> 3, wx = lane & 7;         // 8x8 lane grid
    const int mq = w >> 1, nq = w & 1;               // wave quadrant
    const int m0 = blockIdx.y * 128, n0 = blockIdx.x * 64;

    // staging assignments
    const int arow = tid >> 1;              // 0..127
    const int ak   = (tid & 1) * 8;         // 0 or 8
    const int acol = arow + ((arow >> 5) << 2);      // cmap(arow)
    const int brow = tid >> 2;              // 0..63
    const int bk   = (tid & 3) * 4;         // 0,4,8,12
    const int bcol = brow + ((brow >> 5) << 2);      // cmap(brow)

    // compute-phase read offsets (conflict-free by construction)
    const int aoff = mq * 72 + wy * 8 + ((wy >> 2) << 2);   // cmap(mq*64+wy*8)
    const int boff = nq * 36 + wx * 4;                      // cmap(nq*32+wx*4)

    const float* Ab = A + (size_t)(m0 + arow) * K + ak;
    const float* Bb = B + (size_t)(n0 + brow) * K + bk;

    float acc[8][4] = {};

    float4 ra0 = *(const float4*)(Ab);
    float4 ra1 = *(const float4*)(Ab + 4);
    float4 rb0 = *(const float4*)(Bb);

    const int NT = K / 16;
    {   // stage tile 0
        float* ap = &As[0][ak][acol];
        ap[0*140]=ra0.x; ap[1*140]=ra0.y; ap[2*140]=ra0.z; ap[3*140]=ra0.w;
        ap[4*140]=ra1.x; ap[5*140]=ra1.y; ap[6*140]=ra1.z; ap[7*140]=ra1.w;
        float* bp = &Bs[0][bk][bcol];
        bp[0*68]=rb0.x; bp[1*68]=rb0.y; bp[2*68]=rb0.z; bp[3*68]=rb0.w;
    }
    __syncthreads();

    #pragma unroll 1
    for (int t = 0; t < NT; ++t) {
        const int cur = t & 1;
        if (t + 1 < NT) {                  // issue next-tile loads under FMAs
            const int ko = (t + 1) * 16;
            ra0 = *(const float4*)(Ab + ko);
            ra1 = *(const float4*)(Ab + ko + 4);
            rb0 = *(const float4*)(Bb + ko);
        }
        #pragma unroll
        for (int k = 0; k < 16; ++k) {
            float4 a40 = *(const float4*)&As[cur][k][aoff];
            float4 a41 = *(const float4*)&As[cur][k][aoff + 4];
            float4 b40 = *(const float4*)&Bs[cur][k][boff];
            float am[8] = {a40.x,a40.y,a40.z,a40.w,a41.x,a41.y,a41.z,a41.w};
            float bn[4] = {b40.x,b40.y,b40.z,b40.w};
            #pragma unroll
            for (int i = 0; i < 8; ++i)
                #pragma unroll
                for (int j = 0; j < 4; ++j)
                    acc[i][j] += am[i] * bn[j];
        }
        if (t + 1 < NT) {                  // stage into OTHER buffer; single
            const int nxt = (t + 1) & 1;   // barrier per tile
            float* ap = &As[nxt][ak][acol];
            ap[0*140]=ra0.x; ap[1*140]=ra0.y; ap[2*140]=ra0.z; ap[3*140]=ra0.w;
            ap[4*140]=ra1.x; ap[5*140]=ra1.y; ap[6*140]=ra1.z; ap[7*140]=ra1.w;
            float* bp = &Bs[nxt][bk][bcol];
            bp[0*68]=rb0.x; bp[1*68]=rb0.y; bp[2*68]=rb0.z; bp[3*68]=rb0.w;
            __syncthreads();
        }
    }

    const float invL = DIV_L ? (1.0f / *Lptr) : 1.0f;
    #pragma unroll
    for (int i = 0; i < 8; ++i) {
        size_t row = (size_t)(m0 + mq*64 + wy*8 + i);
        float* Cp = C + row * N + n0 + nq*32 + wx*4;
        float4 rv;
        rv.x=acc[i][0]; rv.y=acc[i][1]; rv.z=acc[i][2]; rv.w=acc[i][3];
        if (DIV_L) { rv.x*=invL; rv.y*=invL; rv.z*=invL; rv.w*=invL; }
        if (HAS_ADD) {
            float4 ad = *(const float4*)(addM + row * N + n0 + nq*32 + wx*4);
            rv.x+=ad.x; rv.y+=ad.y; rv.z+=ad.z; rv.w+=ad.w;
        }
        *(float4*)(Cp) = rv;
    }
}

// ============================================================================
// Spectral density from sparse z (deterministic two-stage)
// ============================================================================
__global__ void sparse_density_stage1(const int* __restrict__ sidx,
                                      const float* __restrict__ sval,
                                      float* __restrict__ partial)
{
    const int w = threadIdx.x;            // 512
    const int blk = blockIdx.x;           // 64 blocks x 64 rows
    const int base = blk * 64 * 10;
    float acc = 0.0f;
    for (int e = 0; e < 640; ++e) {
        int d = sidx[base + e];
        float v = sval[base + e];
        if ((d & 511) == w) acc += v * v;
    }
    partial[blk * 512 + w] = acc;
}

// ============================================================================
// prev_windows spectral density
// ============================================================================
__global__ void prev_density_stage1(const float* __restrict__ pw, float* __restrict__ partial)
{
    const int p = blockIdx.x, chunk = blockIdx.y;   // (8, 64)
    const int w = threadIdx.x;                      // 512
    const float* base = pw + ((size_t)p * BATCH + (size_t)chunk * 64) * DIM;
    float acc = 0.0f;
    for (int i = 0; i < 64; ++i) {
        float a = base[(size_t)i * DIM + w];
        float c = base[(size_t)i * DIM + 512 + w];
        acc += a * a + c * c;
    }
    partial[((size_t)(p * 64 + chunk)) * 512 + w] = acc;
}

__global__ void prev_density_stage2(const float* __restrict__ partial, float* __restrict__ mD_prev)
{
    const int p = blockIdx.x; const int w = threadIdx.x;
    float acc = 0.0f;
    for (int i = 0; i < 64; ++i) acc += partial[((size_t)(p * 64 + i)) * 512 + w];
    mD_prev[p * 512 + w] = acc;
}

// ============================================================================
// Fused: mD1 = col-sum of partials; normalize; attention logits; softmax.
// ============================================================================
__device__ __forceinline__ float wave_fmax(float v) {
    #pragma unroll
    for (int m = 1; m < 64; m <<= 1) v = fmaxf(v, __shfl_xor(v, m));
    return v;
}
__device__ __forceinline__ float wave_fmin(float v) {
    #pragma unroll
    for (int m = 1; m < 64; m <<= 1) v = fminf(v, __shfl_xor(v, m));
    return v;
}
__device__ __forceinline__ float wave_fsum(float v) {
    #pragma unroll
    for (int m = 1; m < 64; m <<= 1) v += __shfl_xor(v, m);
    return v;
}

__global__ void density2_attention(const float* __restrict__ partial,
                                   const float* __restrict__ mD_prev,
                                   float* __restrict__ att)
{
    __shared__ float md1[512];
    __shared__ float att_l[PPREV];
    const int tid = threadIdx.x, lane = tid & 63, w = tid >> 6;
    float v = 0.0f;
    for (int i = 0; i < 64; ++i) v += partial[i * 512 + tid];
    md1[tid] = v;
    __syncthreads();
    float t8[8], u8[8];
    {
        const float4* m4 = (const float4*)(&md1[lane * 8]);
        float4 a = m4[0], bq = m4[1];
        t8[0]=a.x; t8[1]=a.y; t8[2]=a.z; t8[3]=a.w; t8[4]=bq.x; t8[5]=bq.y; t8[6]=bq.z; t8[7]=bq.w;
        const float4* p4 = (const float4*)(mD_prev + w * 512 + lane * 8);
        float4 c = p4[0], d = p4[1];
        u8[0]=c.x; u8[1]=c.y; u8[2]=c.z; u8[3]=c.w; u8[4]=d.x; u8[5]=d.y; u8[6]=d.z; u8[7]=d.w;
    }
    float mx = t8[0], mn = t8[0], pmx = u8[0], pmn = u8[0];
    #pragma unroll
    for (int i = 1; i < 8; ++i) {
        mx = fmaxf(mx, t8[i]); mn = fminf(mn, t8[i]);
        pmx = fmaxf(pmx, u8[i]); pmn = fminf(pmn, u8[i]);
    }
    mx = wave_fmax(mx); mn = wave_fmin(mn);
    pmx = wave_fmax(pmx); pmn = wave_fmin(pmn);
    const float inv  = 1.0f / (mx - mn + 1e-8f);
    const float pinv = 1.0f / (pmx - pmn + 1e-8f);
    float dot = 0.0f;
    #pragma unroll
    for (int i = 0; i < 8; ++i) dot += ((u8[i] - pmn) * pinv) * ((t8[i] - mn) * inv);
    dot = wave_fsum(dot);
    if (lane == 0) att_l[w] = dot / 22.627417f;   // np.float32(sqrt(512))
    __syncthreads();
    if (tid == 0) {
        float m = att_l[0];
        #pragma unroll
        for (int p = 1; p < PPREV; ++p) m = fmaxf(m, att_l[p]);
        float e[PPREV], s = 0.0f;
        #pragma unroll
        for (int p = 0; p < PPREV; ++p) { e[p] = expf(att_l[p] - m); s += e[p]; }
        #pragma unroll
        for (int p = 0; p < PPREV; ++p) att[p] = e[p] / s;
    }
}

// ============================================================================
// z_att = lambda2 * sum_p clip(pw[p], +-150) * att[p]
// ============================================================================
__global__ __launch_bounds__(256)
void weighted_sum(const float* __restrict__ pw, const float* __restrict__ att,
                  const float* __restrict__ lam, float* __restrict__ zatt)
{
    const size_t i = ((size_t)blockIdx.x * 256 + threadIdx.x) * 4;
    const float l2 = *lam;
    float a[PPREV];
    #pragma unroll
    for (int p = 0; p < PPREV; ++p) a[p] = att[p];
    float4 acc = make_float4(0.f, 0.f, 0.f, 0.f);
    #pragma unroll
    for (int p = 0; p < PPREV; ++p) {
        float4 v = *(const float4*)(pw + (size_t)p * BATCH * DIM + i);
        v.x = fminf(fmaxf(v.x, -150.f), 150.f);
        v.y = fminf(fmaxf(v.y, -150.f), 150.f);
        v.z = fminf(fmaxf(v.z, -150.f), 150.f);
        v.w = fminf(fmaxf(v.w, -150.f), 150.f);
        acc.x += v.x * a[p]; acc.y += v.y * a[p]; acc.z += v.z * a[p]; acc.w += v.w * a[p];
    }
    acc.x *= l2; acc.y *= l2; acc.z *= l2; acc.w *= l2;
    *(float4*)(zatt + i) = acc;
}

// ============================================================================
// Final: mD2 = col-sum of partials, min-max normalize into out[0:512]
// ============================================================================
__global__ void finalize_fused(const float* __restrict__ partial, float* __restrict__ out)
{
    __shared__ float red[512];
    const int tid = threadIdx.x;
    float v = 0.0f;
    for (int i = 0; i < 64; ++i) v += partial[i * 512 + tid];
    red[tid] = v; __syncthreads();
    for (int off = 256; off > 0; off >>= 1) { if (tid < off) red[tid] = fmaxf(red[tid], red[tid+off]); __syncthreads(); }
    float mx = red[0]; __syncthreads();
    red[tid] = v; __syncthreads();
    for (int off = 256; off > 0; off >>= 1) { if (tid < off) red[tid] = fminf(red[tid], red[tid+off]); __syncthreads(); }
    float mn = red[0];
    out[tid] = (v - mn) / (mx - mn + 1e-8f);
}

// ============================================================================
extern "C" void kernel_launch(void* const* d_in, const int* in_sizes, int n_in,
                              void* d_out, int out_size, void* d_ws, size_t ws_size,
                              hipStream_t stream)
{
    const float* x   = (const float*)d_in[0];   // [4096,1024]
    const float* pw  = (const float*)d_in[1];   // [8,4096,1024]
    const float* Wd  = (const float*)d_in[2];   // [1,1024,1024]
    const float* S   = (const float*)d_in[3];   // [1,1024,1024] (numerically symmetric)
    const float* lam = (const float*)d_in[4];   // scalar
    const float* L   = (const float*)d_in[5];   // scalar
    float* out = (float*)d_out;                 // [512] ++ [4096*1024]

    float* b       = (float*)d_ws;                      // 4,194,304
    float* zatt    = b + (size_t)BATCH * DIM;           // 4,194,304
    float* pp_prev = zatt + (size_t)BATCH * DIM;        // 262,144
    float* pp_dens = pp_prev + 262144;                  // 32,768
    float* mD_prev = pp_dens + 32768;                   // 4096
    float* attw    = mD_prev + 4096;                    // 8
    float* sval1   = attw + 8;                          // 40,960
    float* sval2   = sval1 + 40960;                     // 40,960
    int*   sidx1   = (int*)(sval2 + 40960);             // 40,960 ints
    int*   sidx2   = sidx1 + 40960;                     // 40,960 ints

    float* c1   = out + 512;   // stage c1 in output z region (rewritten by loop_rows)
    float* zout = out + 512;

    const dim3 gg(DIM / 64, BATCH / 128);   // (16, 32) = 512 blocks = 2/CU

    gemm_cf<true,  false><<<gg, 256, 0, stream>>>(x, Wd, nullptr, b, L, BATCH, DIM, DIM);
    warmup_rows<<<BATCH, 256, 0, stream>>>(b, S, sidx1, sval1);
    sparse_density_stage1<<<64, 512, 0, stream>>>(sidx1, sval1, pp_dens);
    prev_density_stage1<<<dim3(PPREV, 64), 512, 0, stream>>>(pw, pp_prev);
    prev_density_stage2<<<PPREV, 512, 0, stream>>>(pp_prev, mD_prev);
    density2_attention<<<1, 512, 0, stream>>>(pp_dens, mD_prev, attw);
    weighted_sum<<<(BATCH * DIM) / 1024, 256, 0, stream>>>(pw, attw, lam, zatt);
    gemm_cf<false, true ><<<gg, 256, 0, stream>>>(zatt, S, b, c1, nullptr, BATCH, DIM, DIM);
    loop_rows<<<BATCH, 256, 0, stream>>>(c1, b, S, zout, sidx2, sval2);
    sparse_density_stage1<<<64, 512, 0, stream>>>(sidx2, sval2, pp_dens);
    finalize_fused<<<1, 512, 0, stream>>>(pp_dens, out);
}

// Round 10
// 521.293 us; speedup vs baseline: 1.1551x; 1.1551x over previous
//
#include <hip/hip_runtime.h>
#include <stdint.h>

#define BATCH 4096
#define DIM   1024
#define PPREV 8
#define CAPW  64    // per-wave candidate capacity

// popcount of mask over lanes strictly below the current lane
__device__ __forceinline__ int lt_count(unsigned long long m) {
    return __builtin_amdgcn_mbcnt_hi((unsigned)(m >> 32),
           __builtin_amdgcn_mbcnt_lo((unsigned)m, 0));
}
__device__ __forceinline__ bool kp_gt(int ak, int ap, int bk, int bp) {
    return (ak > bk) || (ak == bk && ap > bp);
}

// ============================================================================
// Block-cooperative top-10 by |value|, exact jax.lax.top_k tie-break (lowest
// flat index wins among ties). 256 threads/row; thread owns j = tid*4+t.
// Key = |f32 bits| (int compare == magnitude compare);
// payload = ((1023-j)<<1)|sign -> (key,pay) lex-desc == (value desc, idx asc).
// Fast path: 2 barriers (compact+count | rank+winners).
// ============================================================================
template<bool SEEDED>
__device__ __forceinline__ void select10_blk(
    const float cz[4], int tid, int lane, int wid,
    int2 (*s_cand)[CAPW], int2* s_win, int* s_cnt, int2* s_red, int* s_bnd,
    int& tbits, int wi[10], float wv[10])
{
    int k[4], pay[4];
    #pragma unroll
    for (int t = 0; t < 4; ++t) {
        int bb = __float_as_int(cz[t]);
        k[t]   = bb & 0x7fffffff;
        pay[t] = ((1023 - (tid * 4 + t)) << 1) | (int)((unsigned)bb >> 31);
    }

    if (!SEEDED) {
        // valid lower bound for the 10th-largest: per wave, the 10th-largest
        // of its 64 per-lane maxima; block bound = max over waves.
        int lm = max(max(k[0], k[1]), max(k[2], k[3]));
        #pragma unroll
        for (int k2 = 2; k2 <= 64; k2 <<= 1) {
            #pragma unroll
            for (int j = k2 >> 1; j > 0; j >>= 1) {
                int p = __shfl_xor(lm, j);
                bool keep_max = (((lane & k2) == 0) == ((lane & j) == 0));
                if ((p > lm) == keep_max) lm = p;
            }
        }
        int wb = __builtin_amdgcn_readlane(lm, 9);
        if (lane == 0) s_bnd[wid] = wb;
        __syncthreads();
        tbits = max(max(s_bnd[0], s_bnd[1]), max(s_bnd[2], s_bnd[3]));
    }

    int tb = tbits;
    int c0, c1, c2, c3, total; bool bad;
    #pragma unroll 1
    for (;;) {
        unsigned long long b0 = __ballot(k[0] >= tb);
        unsigned long long b1 = __ballot(k[1] >= tb);
        unsigned long long b2 = __ballot(k[2] >= tb);
        unsigned long long b3 = __ballot(k[3] >= tb);
        int pos = lt_count(b0);
        if (k[0] >= tb && pos < CAPW) s_cand[wid][pos] = make_int2(k[0], pay[0]);
        int base = __popcll(b0);
        pos = base + lt_count(b1);
        if (k[1] >= tb && pos < CAPW) s_cand[wid][pos] = make_int2(k[1], pay[1]);
        base += __popcll(b1);
        pos = base + lt_count(b2);
        if (k[2] >= tb && pos < CAPW) s_cand[wid][pos] = make_int2(k[2], pay[2]);
        base += __popcll(b2);
        pos = base + lt_count(b3);
        if (k[3] >= tb && pos < CAPW) s_cand[wid][pos] = make_int2(k[3], pay[3]);
        base += __popcll(b3);
        if (lane == 0) s_cnt[wid] = base;
        __syncthreads();                               // barrier 1
        c0 = s_cnt[0]; c1 = s_cnt[1]; c2 = s_cnt[2]; c3 = s_cnt[3];
        total = c0 + c1 + c2 + c3;
        bad = (c0 > CAPW) || (c1 > CAPW) || (c2 > CAPW) || (c3 > CAPW);
        if (total >= 10 || tb == 0) break;
        tb = (tb > 0x00800000) ? (tb - 0x00800000) : 0;   // halve threshold
        __syncthreads();
    }

    if (!bad) {
        if (tid < total) {
            int w, e;
            if      (tid < c0)           { w = 0; e = tid; }
            else if (tid < c0 + c1)      { w = 1; e = tid - c0; }
            else if (tid < c0 + c1 + c2) { w = 2; e = tid - c0 - c1; }
            else                         { w = 3; e = tid - c0 - c1 - c2; }
            int2 mine = s_cand[w][e];
            int cns[4] = {c0, c1, c2, c3};
            int rank = 0;
            #pragma unroll
            for (int w2 = 0; w2 < 4; ++w2) {
                const int cn = cns[w2];
                const int2* reg = s_cand[w2];
                int e2 = 0;
                #pragma unroll 1
                for (; e2 + 4 <= cn; e2 += 4) {
                    int2 q0 = reg[e2], q1 = reg[e2+1], q2 = reg[e2+2], q3 = reg[e2+3];
                    rank += kp_gt(q0.x, q0.y, mine.x, mine.y) ? 1 : 0;
                    rank += kp_gt(q1.x, q1.y, mine.x, mine.y) ? 1 : 0;
                    rank += kp_gt(q2.x, q2.y, mine.x, mine.y) ? 1 : 0;
                    rank += kp_gt(q3.x, q3.y, mine.x, mine.y) ? 1 : 0;
                }
                #pragma unroll 1
                for (; e2 < cn; ++e2) {
                    int2 q = reg[e2];
                    rank += kp_gt(q.x, q.y, mine.x, mine.y) ? 1 : 0;
                }
            }
            if (rank < 10) s_win[rank] = mine;
        }
        __syncthreads();                               // barrier 2
    } else {
        #pragma unroll 1
        for (int r = 0; r < 10; ++r) {
            int bk = k[0], bp = pay[0];
            #pragma unroll
            for (int t = 1; t < 4; ++t)
                if (kp_gt(k[t], pay[t], bk, bp)) { bk = k[t]; bp = pay[t]; }
            #pragma unroll
            for (int m = 1; m < 64; m <<= 1) {
                int ok = __shfl_xor(bk, m), op = __shfl_xor(bp, m);
                if (kp_gt(ok, op, bk, bp)) { bk = ok; bp = op; }
            }
            if (lane == 0) s_red[wid] = make_int2(bk, bp);
            __syncthreads();
            if (tid == 0) {
                int2 best = s_red[0];
                #pragma unroll
                for (int w2 = 1; w2 < 4; ++w2) {
                    int2 cc = s_red[w2];
                    if (kp_gt(cc.x, cc.y, best.x, best.y)) best = cc;
                }
                s_win[r] = best;
            }
            __syncthreads();
            int2 wr = s_win[r];
            #pragma unroll
            for (int t = 0; t < 4; ++t)
                if (k[t] == wr.x && pay[t] == wr.y) k[t] = -1;
        }
    }

    #pragma unroll
    for (int r = 0; r < 10; ++r) {
        int2 wr = s_win[r];
        wi[r] = 1023 - (wr.y >> 1);
        wv[r] = __int_as_float(wr.x | ((wr.y & 1) << 31));
    }
    tbits = __float_as_int(wv[9]) & 0x7fffffff;
}

// c = b + sum_k wv[k] * S[wi[k], :]
__device__ __forceinline__ void gather_block(const float bz[4], float cz[4],
                                             const float* __restrict__ S,
                                             const int wi[10], const float wv[10], int tid)
{
    #pragma unroll
    for (int t = 0; t < 4; ++t) cz[t] = bz[t];
    #pragma unroll
    for (int kk = 0; kk < 10; ++kk) {
        int row = __builtin_amdgcn_readfirstlane(wi[kk]);
        const float wvs = wv[kk];
        float4 v = *(const float4*)(S + (size_t)row * DIM + tid * 4);
        cz[0] += wvs * v.x;
        cz[1] += wvs * v.y;
        cz[2] += wvs * v.z;
        cz[3] += wvs * v.w;
    }
}

// ============================================================================
// Warm-up: z=thr(b); c=b+z@S^T; z=thr(c) -> sparse (idx,val). 1 block/row.
// ============================================================================
__global__ __launch_bounds__(256)
void warmup_rows(const float* __restrict__ b, const float* __restrict__ S,
                 int* __restrict__ sidx, float* __restrict__ sval)
{
    __shared__ int2 s_cand[4][CAPW];
    __shared__ int2 s_win[10];
    __shared__ int2 s_red[4];
    __shared__ int  s_cnt[4];
    __shared__ int  s_bnd[4];
    const int tid = threadIdx.x, lane = tid & 63, wid = tid >> 6;
    const int r = blockIdx.x;
    float4 bv = *(const float4*)(b + (size_t)r * DIM + tid * 4);
    float bz[4] = {bv.x, bv.y, bv.z, bv.w};
    int wi[10]; float wv[10]; int tbits = 0;
    select10_blk<false>(bz, tid, lane, wid, s_cand, s_win, s_cnt, s_red, s_bnd, tbits, wi, wv);
    float cz[4];
    gather_block(bz, cz, S, wi, wv, tid);
    select10_blk<true>(cz, tid, lane, wid, s_cand, s_win, s_cnt, s_red, s_bnd, tbits, wi, wv);
    if (tid < 10) {
        int2 wr = s_win[tid];
        sidx[r * 10 + tid] = 1023 - (wr.y >> 1);
        sval[r * 10 + tid] = __int_as_float(wr.x | ((wr.y & 1) << 31));
    }
}

// ============================================================================
// Main loop: z=thr(c1); 9 x { c=b+z@S^T; z=thr(c) } with fixed-point exit.
// ============================================================================
__global__ __launch_bounds__(256)
void loop_rows(const float* __restrict__ c1, const float* __restrict__ b,
               const float* __restrict__ S, float* __restrict__ zout,
               int* __restrict__ sidx, float* __restrict__ sval)
{
    __shared__ int2 s_cand[4][CAPW];
    __shared__ int2 s_win[10];
    __shared__ int2 s_red[4];
    __shared__ int  s_cnt[4];
    __shared__ int  s_bnd[4];
    const int tid = threadIdx.x, lane = tid & 63, wid = tid >> 6;
    const int r = blockIdx.x;
    float4 bv = *(const float4*)(b  + (size_t)r * DIM + tid * 4);
    float4 cv = *(const float4*)(c1 + (size_t)r * DIM + tid * 4);
    float bz[4] = {bv.x, bv.y, bv.z, bv.w};
    float cz[4] = {cv.x, cv.y, cv.z, cv.w};
    int wi[10]; float wv[10]; int tbits = 0;
    select10_blk<false>(cz, tid, lane, wid, s_cand, s_win, s_cnt, s_red, s_bnd, tbits, wi, wv);
    int pwi[10], pwb[10];
    #pragma unroll 1
    for (int it = 0; it < 9; ++it) {
        #pragma unroll
        for (int kk = 0; kk < 10; ++kk) { pwi[kk] = wi[kk]; pwb[kk] = __float_as_int(wv[kk]); }
        gather_block(bz, cz, S, wi, wv, tid);
        select10_blk<true>(cz, tid, lane, wid, s_cand, s_win, s_cnt, s_red, s_bnd, tbits, wi, wv);
        bool same = true;
        #pragma unroll
        for (int kk = 0; kk < 10; ++kk)
            same = same && (wi[kk] == pwi[kk]) && (__float_as_int(wv[kk]) == pwb[kk]);
        if (same) break;
    }
    float e[4];
    #pragma unroll
    for (int t = 0; t < 4; ++t) {
        const int j = tid * 4 + t;
        float v = 0.0f;
        #pragma unroll
        for (int kk = 0; kk < 10; ++kk) v = (wi[kk] == j) ? wv[kk] : v;
        e[t] = v;
    }
    float4 o; o.x = e[0]; o.y = e[1]; o.z = e[2]; o.w = e[3];
    *(float4*)(zout + (size_t)r * DIM + tid * 4) = o;
    if (tid < 10) {
        int2 wr = s_win[tid];
        sidx[r * 10 + tid] = 1023 - (wr.y >> 1);
        sval[r * 10 + tid] = __int_as_float(wr.x | ((wr.y & 1) << 31));
    }
}

// ============================================================================
// GEMM: C[m,n] = (sum_k A[m,k]*B[n,k]) [/L] [+ add[m,n]]  (C = A @ B^T)
// 128x128 tile, BK=16, 512 threads = 8 waves (2 waves/SIMD within ONE block
// -> latency hiding does not depend on multi-block residency). Wave grid
// 2x4 (64x32 per wave), lane grid 8x8, 8x4 per thread.
// cmap(m)=m+(m>>5)*4 column placement: both operand reads are 8-address
// multicast hitting 8 DISTINCT bank quads (32/32 banks, conflict-free).
// Double-buffered LDS, ONE barrier per K-tile, register prefetch.
// Grid 256 = 1 block/CU.
// ============================================================================
template<bool DIV_L, bool HAS_ADD>
__global__ __launch_bounds__(512)
void gemm512(const float* __restrict__ A, const float* __restrict__ B,
             const float* __restrict__ addM, float* __restrict__ C,
             const float* __restrict__ Lptr, int M, int N, int K)
{
    __shared__ __align__(16) float As[2][16][140];   // 128 cols via cmap (<=139)
    __shared__ __align__(16) float Bs[2][16][140];
    const int tid  = threadIdx.x;                    // 0..511
    const int lane = tid & 63, w = tid >> 6;         // 8 waves
    const int wy = lane >> 3, wx = lane & 7;         // 8x8 lane grid
    const int mq = w >> 2, nq = w & 3;               // 2x4 wave grid
    const int m0 = blockIdx.y * 128, n0 = blockIdx.x * 128;

    // staging: one float4 of A and of B per thread
    const int srow = tid >> 2;                       // 0..127
    const int sk   = (tid & 3) * 4;                  // 0,4,8,12
    const int scol = srow + ((srow >> 5) << 2);      // cmap(srow)

    // compute-phase read offsets (conflict-free, 16B aligned)
    const int am_ = mq * 64 + wy * 8;
    const int aoff = am_ + ((am_ >> 5) << 2);        // cmap, contiguous 8
    const int bn_ = nq * 32 + wx * 4;
    const int boff = bn_ + ((bn_ >> 5) << 2);        // cmap, contiguous 4

    const float* Ab = A + (size_t)(m0 + srow) * K + sk;
    const float* Bb = B + (size_t)(n0 + srow) * K + sk;

    float acc[8][4] = {};

    float4 ra = *(const float4*)(Ab);
    float4 rb = *(const float4*)(Bb);

    const int NT = K / 16;
    {   // stage tile 0
        float* ap = &As[0][sk][scol];
        ap[0*140]=ra.x; ap[1*140]=ra.y; ap[2*140]=ra.z; ap[3*140]=ra.w;
        float* bp = &Bs[0][sk][scol];
        bp[0*140]=rb.x; bp[1*140]=rb.y; bp[2*140]=rb.z; bp[3*140]=rb.w;
    }
    __syncthreads();

    #pragma unroll 1
    for (int t = 0; t < NT; ++t) {
        const int cur = t & 1;
        if (t + 1 < NT) {                  // next-tile loads issue under FMAs
            const int ko = (t + 1) * 16;
            ra = *(const float4*)(Ab + ko);
            rb = *(const float4*)(Bb + ko);
        }
        #pragma unroll
        for (int k = 0; k < 16; ++k) {
            float4 a40 = *(const float4*)&As[cur][k][aoff];
            float4 a41 = *(const float4*)&As[cur][k][aoff + 4];
            float4 b40 = *(const float4*)&Bs[cur][k][boff];
            float am[8] = {a40.x,a40.y,a40.z,a40.w,a41.x,a41.y,a41.z,a41.w};
            float bn[4] = {b40.x,b40.y,b40.z,b40.w};
            #pragma unroll
            for (int i = 0; i < 8; ++i)
                #pragma unroll
                for (int j = 0; j < 4; ++j)
                    acc[i][j] += am[i] * bn[j];
        }
        if (t + 1 < NT) {                  // stage OTHER buffer; single barrier
            const int nxt = (t + 1) & 1;
            float* ap = &As[nxt][sk][scol];
            ap[0*140]=ra.x; ap[1*140]=ra.y; ap[2*140]=ra.z; ap[3*140]=ra.w;
            float* bp = &Bs[nxt][sk][scol];
            bp[0*140]=rb.x; bp[1*140]=rb.y; bp[2*140]=rb.z; bp[3*140]=rb.w;
            __syncthreads();
        }
    }

    const float invL = DIV_L ? (1.0f / *Lptr) : 1.0f;
    #pragma unroll
    for (int i = 0; i < 8; ++i) {
        size_t row = (size_t)(m0 + mq*64 + wy*8 + i);
        float* Cp = C + row * N + n0 + nq*32 + wx*4;
        float4 rv;
        rv.x=acc[i][0]; rv.y=acc[i][1]; rv.z=acc[i][2]; rv.w=acc[i][3];
        if (DIV_L) { rv.x*=invL; rv.y*=invL; rv.z*=invL; rv.w*=invL; }
        if (HAS_ADD) {
            float4 ad = *(const float4*)(addM + row * N + n0 + nq*32 + wx*4);
            rv.x+=ad.x; rv.y+=ad.y; rv.z+=ad.z; rv.w+=ad.w;
        }
        *(float4*)(Cp) = rv;
    }
}

// ============================================================================
// Spectral density from sparse z (deterministic two-stage)
// ============================================================================
__global__ void sparse_density_stage1(const int* __restrict__ sidx,
                                      const float* __restrict__ sval,
                                      float* __restrict__ partial)
{
    const int w = threadIdx.x;            // 512
    const int blk = blockIdx.x;           // 64 blocks x 64 rows
    const int base = blk * 64 * 10;
    float acc = 0.0f;
    for (int e = 0; e < 640; ++e) {
        int d = sidx[base + e];
        float v = sval[base + e];
        if ((d & 511) == w) acc += v * v;
    }
    partial[blk * 512 + w] = acc;
}

// ============================================================================
// prev_windows spectral density
// ============================================================================
__global__ void prev_density_stage1(const float* __restrict__ pw, float* __restrict__ partial)
{
    const int p = blockIdx.x, chunk = blockIdx.y;   // (8, 64)
    const int w = threadIdx.x;                      // 512
    const float* base = pw + ((size_t)p * BATCH + (size_t)chunk * 64) * DIM;
    float acc = 0.0f;
    for (int i = 0; i < 64; ++i) {
        float a = base[(size_t)i * DIM + w];
        float c = base[(size_t)i * DIM + 512 + w];
        acc += a * a + c * c;
    }
    partial[((size_t)(p * 64 + chunk)) * 512 + w] = acc;
}

__global__ void prev_density_stage2(const float* __restrict__ partial, float* __restrict__ mD_prev)
{
    const int p = blockIdx.x; const int w = threadIdx.x;
    float acc = 0.0f;
    for (int i = 0; i < 64; ++i) acc += partial[((size_t)(p * 64 + i)) * 512 + w];
    mD_prev[p * 512 + w] = acc;
}

// ============================================================================
// Fused: mD1 = col-sum of partials; normalize; attention logits; softmax.
// ============================================================================
__device__ __forceinline__ float wave_fmax(float v) {
    #pragma unroll
    for (int m = 1; m < 64; m <<= 1) v = fmaxf(v, __shfl_xor(v, m));
    return v;
}
__device__ __forceinline__ float wave_fmin(float v) {
    #pragma unroll
    for (int m = 1; m < 64; m <<= 1) v = fminf(v, __shfl_xor(v, m));
    return v;
}
__device__ __forceinline__ float wave_fsum(float v) {
    #pragma unroll
    for (int m = 1; m < 64; m <<= 1) v += __shfl_xor(v, m);
    return v;
}

__global__ void density2_attention(const float* __restrict__ partial,
                                   const float* __restrict__ mD_prev,
                                   float* __restrict__ att)
{
    __shared__ float md1[512];
    __shared__ float att_l[PPREV];
    const int tid = threadIdx.x, lane = tid & 63, w = tid >> 6;
    float v = 0.0f;
    for (int i = 0; i < 64; ++i) v += partial[i * 512 + tid];
    md1[tid] = v;
    __syncthreads();
    float t8[8], u8[8];
    {
        const float4* m4 = (const float4*)(&md1[lane * 8]);
        float4 a = m4[0], bq = m4[1];
        t8[0]=a.x; t8[1]=a.y; t8[2]=a.z; t8[3]=a.w; t8[4]=bq.x; t8[5]=bq.y; t8[6]=bq.z; t8[7]=bq.w;
        const float4* p4 = (const float4*)(mD_prev + w * 512 + lane * 8);
        float4 c = p4[0], d = p4[1];
        u8[0]=c.x; u8[1]=c.y; u8[2]=c.z; u8[3]=c.w; u8[4]=d.x; u8[5]=d.y; u8[6]=d.z; u8[7]=d.w;
    }
    float mx = t8[0], mn = t8[0], pmx = u8[0], pmn = u8[0];
    #pragma unroll
    for (int i = 1; i < 8; ++i) {
        mx = fmaxf(mx, t8[i]); mn = fminf(mn, t8[i]);
        pmx = fmaxf(pmx, u8[i]); pmn = fminf(pmn, u8[i]);
    }
    mx = wave_fmax(mx); mn = wave_fmin(mn);
    pmx = wave_fmax(pmx); pmn = wave_fmin(pmn);
    const float inv  = 1.0f / (mx - mn + 1e-8f);
    const float pinv = 1.0f / (pmx - pmn + 1e-8f);
    float dot = 0.0f;
    #pragma unroll
    for (int i = 0; i < 8; ++i) dot += ((u8[i] - pmn) * pinv) * ((t8[i] - mn) * inv);
    dot = wave_fsum(dot);
    if (lane == 0) att_l[w] = dot / 22.627417f;   // np.float32(sqrt(512))
    __syncthreads();
    if (tid == 0) {
        float m = att_l[0];
        #pragma unroll
        for (int p = 1; p < PPREV; ++p) m = fmaxf(m, att_l[p]);
        float e[PPREV], s = 0.0f;
        #pragma unroll
        for (int p = 0; p < PPREV; ++p) { e[p] = expf(att_l[p] - m); s += e[p]; }
        #pragma unroll
        for (int p = 0; p < PPREV; ++p) att[p] = e[p] / s;
    }
}

// ============================================================================
// z_att = lambda2 * sum_p clip(pw[p], +-150) * att[p]
// ============================================================================
__global__ __launch_bounds__(256)
void weighted_sum(const float* __restrict__ pw, const float* __restrict__ att,
                  const float* __restrict__ lam, float* __restrict__ zatt)
{
    const size_t i = ((size_t)blockIdx.x * 256 + threadIdx.x) * 4;
    const float l2 = *lam;
    float a[PPREV];
    #pragma unroll
    for (int p = 0; p < PPREV; ++p) a[p] = att[p];
    float4 acc = make_float4(0.f, 0.f, 0.f, 0.f);
    #pragma unroll
    for (int p = 0; p < PPREV; ++p) {
        float4 v = *(const float4*)(pw + (size_t)p * BATCH * DIM + i);
        v.x = fminf(fmaxf(v.x, -150.f), 150.f);
        v.y = fminf(fmaxf(v.y, -150.f), 150.f);
        v.z = fminf(fmaxf(v.z, -150.f), 150.f);
        v.w = fminf(fmaxf(v.w, -150.f), 150.f);
        acc.x += v.x * a[p]; acc.y += v.y * a[p]; acc.z += v.z * a[p]; acc.w += v.w * a[p];
    }
    acc.x *= l2; acc.y *= l2; acc.z *= l2; acc.w *= l2;
    *(float4*)(zatt + i) = acc;
}

// ============================================================================
// Final: mD2 = col-sum of partials, min-max normalize into out[0:512]
// ============================================================================
__global__ void finalize_fused(const float* __restrict__ partial, float* __restrict__ out)
{
    __shared__ float red[512];
    const int tid = threadIdx.x;
    float v = 0.0f;
    for (int i = 0; i < 64; ++i) v += partial[i * 512 + tid];
    red[tid] = v; __syncthreads();
    for (int off = 256; off > 0; off >>= 1) { if (tid < off) red[tid] = fmaxf(red[tid], red[tid+off]); __syncthreads(); }
    float mx = red[0]; __syncthreads();
    red[tid] = v; __syncthreads();
    for (int off = 256; off > 0; off >>= 1) { if (tid < off) red[tid] = fminf(red[tid], red[tid+off]); __syncthreads(); }
    float mn = red[0];
    out[tid] = (v - mn) / (mx - mn + 1e-8f);
}

// ============================================================================
extern "C" void kernel_launch(void* const* d_in, const int* in_sizes, int n_in,
                              void* d_out, int out_size, void* d_ws, size_t ws_size,
                              hipStream_t stream)
{
    const float* x   = (const float*)d_in[0];   // [4096,1024]
    const float* pw  = (const float*)d_in[1];   // [8,4096,1024]
    const float* Wd  = (const float*)d_in[2];   // [1,1024,1024]
    const float* S   = (const float*)d_in[3];   // [1,1024,1024] (numerically symmetric)
    const float* lam = (const float*)d_in[4];   // scalar
    const float* L   = (const float*)d_in[5];   // scalar
    float* out = (float*)d_out;                 // [512] ++ [4096*1024]

    float* b       = (float*)d_ws;                      // 4,194,304
    float* zatt    = b + (size_t)BATCH * DIM;           // 4,194,304
    float* pp_prev = zatt + (size_t)BATCH * DIM;        // 262,144
    float* pp_dens = pp_prev + 262144;                  // 32,768
    float* mD_prev = pp_dens + 32768;                   // 4096
    float* attw    = mD_prev + 4096;                    // 8
    float* sval1   = attw + 8;                          // 40,960
    float* sval2   = sval1 + 40960;                     // 40,960
    int*   sidx1   = (int*)(sval2 + 40960);             // 40,960 ints
    int*   sidx2   = sidx1 + 40960;                     // 40,960 ints

    float* c1   = out + 512;   // stage c1 in output z region (rewritten by loop_rows)
    float* zout = out + 512;

    const dim3 gg(DIM / 128, BATCH / 128);   // (8, 32) = 256 blocks = 1/CU

    gemm512<true,  false><<<gg, 512, 0, stream>>>(x, Wd, nullptr, b, L, BATCH, DIM, DIM);
    warmup_rows<<<BATCH, 256, 0, stream>>>(b, S, sidx1, sval1);
    sparse_density_stage1<<<64, 512, 0, stream>>>(sidx1, sval1, pp_dens);
    prev_density_stage1<<<dim3(PPREV, 64), 512, 0, stream>>>(pw, pp_prev);
    prev_density_stage2<<<PPREV, 512, 0, stream>>>(pp_prev, mD_prev);
    density2_attention<<<1, 512, 0, stream>>>(pp_dens, mD_prev, attw);
    weighted_sum<<<(BATCH * DIM) / 1024, 256, 0, stream>>>(pw, attw, lam, zatt);
    gemm512<false, true ><<<gg, 512, 0, stream>>>(zatt, S, b, c1, nullptr, BATCH, DIM, DIM);
    loop_rows<<<BATCH, 256, 0, stream>>>(c1, b, S, zout, sidx2, sval2);
    sparse_density_stage1<<<64, 512, 0, stream>>>(sidx2, sval2, pp_dens);
    finalize_fused<<<1, 512, 0, stream>>>(pp_dens, out);
}